// Round 6
// baseline (645.729 us; speedup 1.0000x reference)
//
#include <hip/hip_runtime.h>
#include <hip/hip_bf16.h>

#define S_TOK 8192
#define DM    2048
#define DFF   8192
#define NE    8
#define CAP   1024

typedef __bf16 bf16_t;
typedef __bf16 bf16x8 __attribute__((ext_vector_type(8)));
typedef float  f32x4  __attribute__((ext_vector_type(4)));

__device__ __forceinline__ void load_lds16(const void* g, void* l) {
    __builtin_amdgcn_global_load_lds((const __attribute__((address_space(1))) void*)g,
                                     (__attribute__((address_space(3))) void*)l,
                                     16, 0, 0);
}

// ---------------- Kernel 1: gate logits + argmax — one wave per token ---------------
__global__ __launch_bounds__(256) void gate_argmax(const float* __restrict__ x,
                                                   const float* __restrict__ wg,
                                                   int* __restrict__ eidx) {
    int lane = threadIdx.x & 63, wv = threadIdx.x >> 6;
    int s = blockIdx.x * 4 + wv;
    const float* row = x + (size_t)s * DM;
    float acc[8] = {0.f,0.f,0.f,0.f,0.f,0.f,0.f,0.f};
    for (int kb = 0; kb < DM; kb += 256) {
        int k0 = kb + lane * 4;
        float4 xv = *(const float4*)(row + k0);
        const float* wr = wg + (size_t)k0 * NE;
        float xs[4] = {xv.x, xv.y, xv.z, xv.w};
#pragma unroll
        for (int c = 0; c < 4; ++c) {
            float4 w0 = *(const float4*)(wr + c * 8);
            float4 w1 = *(const float4*)(wr + c * 8 + 4);
            acc[0] += xs[c] * w0.x; acc[1] += xs[c] * w0.y;
            acc[2] += xs[c] * w0.z; acc[3] += xs[c] * w0.w;
            acc[4] += xs[c] * w1.x; acc[5] += xs[c] * w1.y;
            acc[6] += xs[c] * w1.z; acc[7] += xs[c] * w1.w;
        }
    }
#pragma unroll
    for (int off = 32; off > 0; off >>= 1)
#pragma unroll
        for (int e = 0; e < 8; ++e) acc[e] += __shfl_xor(acc[e], off, 64);
    if (lane == 0) {
        float best = acc[0]; int bi = 0;
#pragma unroll
        for (int e = 1; e < 8; ++e) if (acc[e] > best) { best = acc[e]; bi = e; }
        eidx[s] = bi;
    }
}

// ---------------- Kernel 2: slot assignment — single wave, prefetch-pipelined -------
__global__ __launch_bounds__(64) void scatter_slots(const int* __restrict__ eidx,
                                                    int* __restrict__ srcOf) {
    int lane = threadIdx.x;
    unsigned long long below = (lane == 0) ? 0ull : ((1ull << lane) - 1ull);
    for (int i = lane; i < NE * CAP; i += 64) srcOf[i] = -1;

    int cnt[NE] = {0,0,0,0,0,0,0,0};
    int e_cur = eidx[lane];
    for (int it = 0; it < S_TOK / 64; ++it) {
        int e_nxt = (it < S_TOK / 64 - 1) ? eidx[(it + 1) * 64 + lane] : 0;
        int s = it * 64 + lane;
#pragma unroll
        for (int ex = 0; ex < NE; ++ex) {
            unsigned long long m = __ballot(e_cur == ex);
            if (e_cur == ex) {
                int loc = cnt[ex] + __popcll(m & below);
                if (loc < CAP) srcOf[ex * CAP + loc] = s;
            }
            cnt[ex] += __popcll(m);
        }
        e_cur = e_nxt;
    }
}

// ---------------- Kernel 3: gather + f32->bf16 into PRE-SWIZZLED A tile images ------
// abuf: per (e, mt, kt) a 32 KiB image of [256 m][64 k] bf16, row stride 128 B,
// byte addr within image = m*128 + ((kbyte) ^ ((m&7)<<4)).  gload_lds copies linearly.
__global__ __launch_bounds__(256) void pack_rows(const float* __restrict__ x,
                                                 const int* __restrict__ srcOf,
                                                 char* __restrict__ abuf) {
    int slot = blockIdx.x;               // e*1024 + c
    int e = slot >> 10, c = slot & 1023;
    int mt = c >> 8, m = c & 255;
    int src = srcOf[slot];
    int tid = threadIdx.x;
    int kt = tid >> 3, kg = tid & 7;     // kt 0..31, kg 0..7 (8 bf16 per 16 B)
    bf16x8 v = {};
    if (src >= 0) {
        const float4* p = (const float4*)(x + (size_t)src * DM + kt * 64 + kg * 8);
        float4 a = p[0], b = p[1];
        v = bf16x8{(bf16_t)a.x,(bf16_t)a.y,(bf16_t)a.z,(bf16_t)a.w,
                   (bf16_t)b.x,(bf16_t)b.y,(bf16_t)b.z,(bf16_t)b.w};
    }
    size_t img = ((size_t)((e * 4 + mt) * 32 + kt)) << 15;
    int off = m * 128 + ((kg * 16) ^ ((m & 7) << 4));
    *(bf16x8*)(abuf + img + off) = v;
}

// ---------------- Kernel 3b: we f32 -> bf16 PRE-SWIZZLED B tile images --------------
// bbuf: per (e, nt, kt) a 32 KiB image [256 n][64 k] bf16, row stride 128 B,
// 16B block j of row n at offset ((j)^(n&7))*16, holding k = j*8..j*8+7.
__global__ __launch_bounds__(256) void convert_we(const float* __restrict__ we,
                                                  char* __restrict__ bbuf) {
    int blk = blockIdx.x;                // (e*32 + nt)*32 + kt
    int kt = blk & 31;
    int ent = blk >> 5;
    int nt = ent & 31, e = ent >> 5;
    int n = threadIdx.x;                 // 0..255
    const float* src = we + ((size_t)e * DM + kt * 64) * DFF + nt * 256 + n;
    char* dst = bbuf + ((size_t)blk << 15) + n * 128;
    int xa = n & 7;
#pragma unroll
    for (int kg = 0; kg < 8; ++kg) {
        bf16x8 v;
#pragma unroll
        for (int k8 = 0; k8 < 8; ++k8)
            v[k8] = (bf16_t)src[(size_t)(kg * 8 + k8) * DFF];   // coalesced across lanes
        *(bf16x8*)(dst + ((kg ^ xa) << 4)) = v;
    }
}

// ---------------- Kernel 4 (primary): 256x256x64 bf16 GEMM, both operands gload_lds -
__global__ __launch_bounds__(512, 2) void moe_gemm_bf16(const char* __restrict__ abuf,
                                                        const char* __restrict__ bbuf,
                                                        const float* __restrict__ be,
                                                        float* __restrict__ out) {
    __shared__ uint4 smem4[131072 / 16];           // [buf][A 32K | B 32K]
    char* smem = (char*)smem4;

    int bid = blockIdx.x;
    int e  = bid & 7;                   // expert == XCD
    int r  = bid >> 3;
    int mt = r & 3;
    int nt = r >> 2;
    int tid = threadIdx.x, lane = tid & 63, wv = tid >> 6;
    int wm = wv >> 2, wn = wv & 3;      // 2x4 wave grid -> 128x64 per wave
    int lr = lane & 15, g = lane >> 4;

    const char* aImg = abuf + (((size_t)((e * 4 + mt) * 32)) << 15);
    const char* bImg = bbuf + (((size_t)((e * 32 + nt) * 32)) << 15);
    int stOff = tid * 16;

    f32x4 acc[8][4] = {};

    auto issueA = [&](int kt, int buf) {
        const char* src = aImg + ((size_t)kt << 15) + stOff;
        char* dst = smem + buf * 65536 + stOff;
#pragma unroll
        for (int i = 0; i < 4; ++i) load_lds16(src + i * 8192, dst + i * 8192);
    };
    auto issueB = [&](int kt, int buf) {
        const char* src = bImg + ((size_t)kt << 15) + stOff;
        char* dst = smem + buf * 65536 + 32768 + stOff;
#pragma unroll
        for (int i = 0; i < 4; ++i) load_lds16(src + i * 8192, dst + i * 8192);
    };

    issueA(0, 0);
    issueB(0, 0);
    __syncthreads();

    int aRowB = (wm * 128 + lr) * 128;
    int xa = lr & 7;
    int colA[2] = { ((0 * 4 + g) ^ xa) << 4, ((1 * 4 + g) ^ xa) << 4 };

    for (int kt = 0; kt < 32; ++kt) {
        int cur = kt & 1, nxt = cur ^ 1;
        bool nl = (kt < 31);
        const char* aC = smem + cur * 65536;
        const char* bC = aC + 32768;

        if (nl) { issueA(kt + 1, nxt); issueB(kt + 1, nxt); }
        __builtin_amdgcn_sched_barrier(0);   // prefetch issues stay at iter top

#pragma unroll
        for (int mh = 0; mh < 2; ++mh) {
            bf16x8 af[4][2];
#pragma unroll
            for (int mf = 0; mf < 4; ++mf) {
                af[mf][0] = *(const bf16x8*)(aC + aRowB + mh * 8192 + mf * 2048 + colA[0]);
                af[mf][1] = *(const bf16x8*)(aC + aRowB + mh * 8192 + mf * 2048 + colA[1]);
            }
#pragma unroll
            for (int nh = 0; nh < 2; ++nh) {
                bf16x8 bfr[2][2];
#pragma unroll
                for (int nf = 0; nf < 2; ++nf) {
                    int rown = wn * 64 + nh * 32 + nf * 16 + lr;
                    int xb = rown & 7;
#pragma unroll
                    for (int kk = 0; kk < 2; ++kk)
                        bfr[nf][kk] = *(const bf16x8*)(bC + rown * 128 + (((kk * 4 + g) ^ xb) << 4));
                }
                __builtin_amdgcn_s_setprio(1);
#pragma unroll
                for (int mf = 0; mf < 4; ++mf)
#pragma unroll
                    for (int nf = 0; nf < 2; ++nf)
#pragma unroll
                        for (int kk = 0; kk < 2; ++kk)
                            acc[mh * 4 + mf][nh * 2 + nf] =
                                __builtin_amdgcn_mfma_f32_16x16x32_bf16(
                                    af[mf][kk], bfr[nf][kk],
                                    acc[mh * 4 + mf][nh * 2 + nf], 0, 0, 0);
                __builtin_amdgcn_s_setprio(0);
            }
        }
        __syncthreads();
    }

    // epilogue: C/D layout col=lane&15, row=(lane>>4)*4+q
    int orow0 = e * CAP + mt * 256 + wm * 128 + g * 4;
    int ocol0 = nt * 256 + wn * 64 + lr;
#pragma unroll
    for (int nf = 0; nf < 4; ++nf) {
        int oc = ocol0 + nf * 16;
        float bias = be[(size_t)e * DFF + oc];
#pragma unroll
        for (int mf = 0; mf < 8; ++mf) {
            int orow = orow0 + mf * 16;
#pragma unroll
            for (int q = 0; q < 4; ++q)
                out[(size_t)(orow + q) * DFF + oc] = acc[mf][nf][q] + bias;
        }
    }
}

// ---------------- Kernel 4 (fallback, R4-proven): f32-B in-loop conversion ----------
__global__ __launch_bounds__(512, 2) void moe_gemm_f32b(const char* __restrict__ abuf,
                                                        const float* __restrict__ we,
                                                        const float* __restrict__ be,
                                                        float* __restrict__ out) {
    __shared__ uint4 smem4[131072 / 16];
    char* smem = (char*)smem4;

    int bid = blockIdx.x;
    int e  = bid & 7;
    int r  = bid >> 3;
    int mt = r & 3;
    int nt = r >> 2;
    int tid = threadIdx.x, lane = tid & 63, wv = tid >> 6;
    int wm = wv >> 2, wn = wv & 3;
    int lr = lane & 15, g = lane >> 4;

    const char* aImg = abuf + (((size_t)((e * 4 + mt) * 32)) << 15);
    const float* bBase = we + (size_t)e * DM * DFF + (size_t)nt * 256 + lane * 4;
    int stOff = tid * 16;

    f32x4 acc[8][4] = {};
    float bs[16];

    auto issueB = [&](int kt, int h) {
        const float* bp = bBase + (size_t)(kt * 64 + wv * 8 + h * 4) * DFF;
#pragma unroll
        for (int j = 0; j < 4; ++j) {
            float4 t = *(const float4*)(bp + (size_t)j * DFF);
            bs[j * 4 + 0] = t.x; bs[j * 4 + 1] = t.y;
            bs[j * 4 + 2] = t.z; bs[j * 4 + 3] = t.w;
        }
    };
    auto issueA = [&](int kt, int buf) {
        const char* src = aImg + ((size_t)kt << 15) + stOff;
        char* dst = smem + buf * 65536 + stOff;
#pragma unroll
        for (int i = 0; i < 4; ++i) load_lds16(src + i * 8192, dst + i * 8192);
    };
    auto writeB = [&](int buf, int h) {
        char* bL = smem + buf * 65536 + 32768;
#pragma unroll
        for (int i = 0; i < 4; ++i) {
            int n = lane * 4 + i;
            ushort w[4];
#pragma unroll
            for (int j = 0; j < 4; ++j) {
                bf16_t b = (bf16_t)bs[j * 4 + i];
                w[j] = __builtin_bit_cast(unsigned short, b);
            }
            uint2 pk = { (unsigned)w[0] | ((unsigned)w[1] << 16),
                         (unsigned)w[2] | ((unsigned)w[3] << 16) };
            int slot = (n & 7) ^ ((n >> 3) & 7);
            *(uint2*)(bL + n * 128 + (((unsigned)(wv ^ slot)) << 4) + h * 8) = pk;
        }
    };

    issueA(0, 0);
    issueB(0, 0); writeB(0, 0);
    issueB(0, 1); writeB(0, 1);
    __syncthreads();

    int aRow = wm * 128 + lr;
    int bRow = wn * 64 + lr;
    int xa = lr & 7;

    for (int kt = 0; kt < 32; ++kt) {
        int cur = kt & 1, nxt = cur ^ 1;
        bool notlast = (kt < 31);
        const char* aC = smem + cur * 65536;
        const char* bC = aC + 32768;

        if (notlast) { issueA(kt + 1, nxt); issueB(kt + 1, 0); }
        __builtin_amdgcn_sched_barrier(0);

#pragma unroll
        for (int mh = 0; mh < 2; ++mh) {
            bf16x8 af[4][2];
#pragma unroll
            for (int mf = 0; mf < 4; ++mf) {
                int rowm = aRow + (mh * 4 + mf) * 16;
#pragma unroll
                for (int kk = 0; kk < 2; ++kk)
                    af[mf][kk] = *(const bf16x8*)(aC + rowm * 128 + (((kk * 4 + g) ^ xa) << 4));
            }
#pragma unroll
            for (int nh = 0; nh < 2; ++nh) {
                bf16x8 bfr[2][2];
#pragma unroll
                for (int nf = 0; nf < 2; ++nf) {
                    int rown = bRow + (nh * 2 + nf) * 16;
                    int xb = (rown & 7) ^ ((rown >> 3) & 7);
#pragma unroll
                    for (int kk = 0; kk < 2; ++kk)
                        bfr[nf][kk] = *(const bf16x8*)(bC + rown * 128 + (((kk * 4 + g) ^ xb) << 4));
                }
                __builtin_amdgcn_s_setprio(1);
#pragma unroll
                for (int mf = 0; mf < 4; ++mf)
#pragma unroll
                    for (int nf = 0; nf < 2; ++nf)
#pragma unroll
                        for (int kk = 0; kk < 2; ++kk)
                            acc[mh * 4 + mf][nh * 2 + nf] =
                                __builtin_amdgcn_mfma_f32_16x16x32_bf16(
                                    af[mf][kk], bfr[nf][kk],
                                    acc[mh * 4 + mf][nh * 2 + nf], 0, 0, 0);
                __builtin_amdgcn_s_setprio(0);
            }
            if (mh == 0 && notlast) { writeB(nxt, 0); issueB(kt + 1, 1); }
        }
        if (notlast) writeB(nxt, 1);
        __syncthreads();
    }

    int orow0 = e * CAP + mt * 256 + wm * 128 + g * 4;
    int ocol0 = nt * 256 + wn * 64 + lr;
#pragma unroll
    for (int nf = 0; nf < 4; ++nf) {
        int oc = ocol0 + nf * 16;
        float bias = be[(size_t)e * DFF + oc];
#pragma unroll
        for (int mf = 0; mf < 8; ++mf) {
            int orow = orow0 + mf * 16;
#pragma unroll
            for (int q = 0; q < 4; ++q)
                out[(size_t)(orow + q) * DFF + oc] = acc[mf][nf][q] + bias;
        }
    }
}

// ---------------- launcher ----------------------------------------------------------
extern "C" void kernel_launch(void* const* d_in, const int* in_sizes, int n_in,
                              void* d_out, int out_size, void* d_ws, size_t ws_size,
                              hipStream_t stream) {
    const float* x  = (const float*)d_in[0];
    const float* wg = (const float*)d_in[1];
    const float* we = (const float*)d_in[2];
    const float* be = (const float*)d_in[3];
    float* out = (float*)d_out;

    size_t needSmall = 65536 + (size_t)32 * 1048576;                 // meta + abuf
    size_t needBig   = needSmall + (size_t)256 * 1048576;            // + bbuf
    if (ws_size < needSmall) return;

    int* eidx  = (int*)d_ws;
    int* srcOf = eidx + S_TOK;
    char* abuf = (char*)d_ws + 65536;
    char* bbuf = abuf + (size_t)32 * 1048576;

    gate_argmax<<<S_TOK / 4, 256, 0, stream>>>(x, wg, eidx);
    scatter_slots<<<1, 64, 0, stream>>>(eidx, srcOf);
    pack_rows<<<S_TOK, 256, 0, stream>>>(x, srcOf, abuf);

    if (ws_size >= needBig) {
        convert_we<<<NE * 32 * 32, 256, 0, stream>>>(we, bbuf);
        moe_gemm_bf16<<<NE * 4 * 32, 512, 0, stream>>>(abuf, bbuf, be, out);
    } else {
        moe_gemm_f32b<<<NE * 4 * 32, 512, 0, stream>>>(abuf, we, be, out);
    }
}

// Round 7
// 630.284 us; speedup vs baseline: 1.0245x; 1.0245x over previous
//
#include <hip/hip_runtime.h>
#include <hip/hip_bf16.h>

#define S_TOK 8192
#define DM    2048
#define DFF   8192
#define NE    8
#define CAP   1024

typedef __bf16 bf16_t;
typedef __bf16 bf16x8 __attribute__((ext_vector_type(8)));
typedef float  f32x4  __attribute__((ext_vector_type(4)));

__device__ __forceinline__ void load_lds16(const void* g, void* l) {
    __builtin_amdgcn_global_load_lds((const __attribute__((address_space(1))) void*)g,
                                     (__attribute__((address_space(3))) void*)l,
                                     16, 0, 0);
}

// ---------------- Kernel 1: gate logits + argmax — one wave per token ---------------
__global__ __launch_bounds__(256) void gate_argmax(const float* __restrict__ x,
                                                   const float* __restrict__ wg,
                                                   int* __restrict__ eidx) {
    int lane = threadIdx.x & 63, wv = threadIdx.x >> 6;
    int s = blockIdx.x * 4 + wv;
    const float* row = x + (size_t)s * DM;
    float acc[8] = {0.f,0.f,0.f,0.f,0.f,0.f,0.f,0.f};
    for (int kb = 0; kb < DM; kb += 256) {
        int k0 = kb + lane * 4;
        float4 xv = *(const float4*)(row + k0);
        const float* wr = wg + (size_t)k0 * NE;
        float xs[4] = {xv.x, xv.y, xv.z, xv.w};
#pragma unroll
        for (int c = 0; c < 4; ++c) {
            float4 w0 = *(const float4*)(wr + c * 8);
            float4 w1 = *(const float4*)(wr + c * 8 + 4);
            acc[0] += xs[c] * w0.x; acc[1] += xs[c] * w0.y;
            acc[2] += xs[c] * w0.z; acc[3] += xs[c] * w0.w;
            acc[4] += xs[c] * w1.x; acc[5] += xs[c] * w1.y;
            acc[6] += xs[c] * w1.z; acc[7] += xs[c] * w1.w;
        }
    }
#pragma unroll
    for (int off = 32; off > 0; off >>= 1)
#pragma unroll
        for (int e = 0; e < 8; ++e) acc[e] += __shfl_xor(acc[e], off, 64);
    if (lane == 0) {
        float best = acc[0]; int bi = 0;
#pragma unroll
        for (int e = 1; e < 8; ++e) if (acc[e] > best) { best = acc[e]; bi = e; }
        eidx[s] = bi;
    }
}

// ---------------- Kernel 2: slot assignment — single wave, prefetch-pipelined -------
__global__ __launch_bounds__(64) void scatter_slots(const int* __restrict__ eidx,
                                                    int* __restrict__ srcOf) {
    int lane = threadIdx.x;
    unsigned long long below = (lane == 0) ? 0ull : ((1ull << lane) - 1ull);
    for (int i = lane; i < NE * CAP; i += 64) srcOf[i] = -1;

    int cnt[NE] = {0,0,0,0,0,0,0,0};
    int e_cur = eidx[lane];
    for (int it = 0; it < S_TOK / 64; ++it) {
        int e_nxt = (it < S_TOK / 64 - 1) ? eidx[(it + 1) * 64 + lane] : 0;
        int s = it * 64 + lane;
#pragma unroll
        for (int ex = 0; ex < NE; ++ex) {
            unsigned long long m = __ballot(e_cur == ex);
            if (e_cur == ex) {
                int loc = cnt[ex] + __popcll(m & below);
                if (loc < CAP) srcOf[ex * CAP + loc] = s;
            }
            cnt[ex] += __popcll(m);
        }
        e_cur = e_nxt;
    }
}

// ---------------- Kernel 3: gather + f32->bf16, UNIT-ordered pre-swizzled A images --
// A image per (e,mt,kt): 32 KB = [unit0: rows m with bit6==0][unit1: bit6==1],
// within-unit row pos = ((m>>7)<<6)|(m&63), byte = pos*128 + ((kbyte)^((m&7)<<4)).
__global__ __launch_bounds__(256) void pack_rows(const float* __restrict__ x,
                                                 const int* __restrict__ srcOf,
                                                 char* __restrict__ abuf) {
    int slot = blockIdx.x;               // e*1024 + c
    int e = slot >> 10, c = slot & 1023;
    int mt = c >> 8, m = c & 255;
    int src = srcOf[slot];
    int tid = threadIdx.x;
    int kt = tid >> 3, kg = tid & 7;     // kt 0..31, kg 0..7 (8 bf16 per 16 B)
    bf16x8 v = {};
    if (src >= 0) {
        const float4* p = (const float4*)(x + (size_t)src * DM + kt * 64 + kg * 8);
        float4 a = p[0], b = p[1];
        v = bf16x8{(bf16_t)a.x,(bf16_t)a.y,(bf16_t)a.z,(bf16_t)a.w,
                   (bf16_t)b.x,(bf16_t)b.y,(bf16_t)b.z,(bf16_t)b.w};
    }
    size_t img = ((size_t)((e * 4 + mt) * 32 + kt)) << 15;
    int u = (m >> 6) & 1;
    int pos = ((m >> 7) << 6) | (m & 63);
    int off = u * 16384 + pos * 128 + ((kg * 16) ^ ((m & 7) << 4));
    *(bf16x8*)(abuf + img + off) = v;
}

// ---------------- Kernel 3b: we f32 -> bf16, UNIT-ordered pre-swizzled B images -----
// B image per (e,nt,kt): 32 KB = [unit0: rows n bit5==0][unit1: bit5==1],
// pos = ((n>>6)<<5)|(n&31), 16B block j at ((j)^(n&7))*16 holding k=j*8..+7.
__global__ __launch_bounds__(256) void convert_we(const float* __restrict__ we,
                                                  char* __restrict__ bbuf) {
    int blk = blockIdx.x;                // (e*32 + nt)*32 + kt
    int kt = blk & 31;
    int ent = blk >> 5;
    int nt = ent & 31, e = ent >> 5;
    int n = threadIdx.x;                 // 0..255
    const float* src = we + ((size_t)e * DM + kt * 64) * DFF + nt * 256 + n;
    int u = (n >> 5) & 1;
    int pos = ((n >> 6) << 5) | (n & 31);
    char* dst = bbuf + ((size_t)blk << 15) + u * 16384 + pos * 128;
    int xa = n & 7;
#pragma unroll
    for (int kg = 0; kg < 8; ++kg) {
        bf16x8 v;
#pragma unroll
        for (int k8 = 0; k8 < 8; ++k8)
            v[k8] = (bf16_t)src[(size_t)(kg * 8 + k8) * DFF];   // coalesced across lanes
        *(bf16x8*)(dst + ((kg ^ xa) << 4)) = v;
    }
}

// ---- Kernel 4 (primary): 256x256x64, 4-phase/K-tile, counted vmcnt, unit pipeline --
// LDS: 8 unit-buffers x 16KB. Tile t uses buffers 4*(t&1)+{0:A0,1:B0,2:B1,3:A1}.
// Phase p of tile t stages tile (t+1)'s unit p; per-phase vmcnt(6) keeps 3 units
// (6 loads) in flight forever — no vmcnt(0) in the main loop.
__global__ __launch_bounds__(512, 2) void moe_gemm_bf16(const char* __restrict__ abuf,
                                                        const char* __restrict__ bbuf,
                                                        const float* __restrict__ be,
                                                        float* __restrict__ out) {
    __shared__ uint4 smem4[131072 / 16];
    char* smem = (char*)smem4;

    int bid = blockIdx.x;
    int e  = bid & 7;                   // expert == XCD
    int r  = bid >> 3;
    int mt = r & 3;
    int nt = r >> 2;
    int tid = threadIdx.x, lane = tid & 63, wv = tid >> 6;
    int wm = wv >> 2, wn = wv & 3;      // 2x4 wave grid -> 128x64 per wave
    int lr = lane & 15, g = lane >> 4;

    const char* aI = abuf + (((size_t)((e * 4 + mt) * 32)) << 15);
    const char* bI = bbuf + (((size_t)((e * 32 + nt) * 32)) << 15);
    int stOff = tid * 16;

    f32x4 acc[8][4] = {};
    bf16x8 af[4][2], bf0[2][2], bf1[2][2];

    int colx[2] = { ((0 * 4 + g) ^ (lr & 7)) << 4, ((1 * 4 + g) ^ (lr & 7)) << 4 };
    int posA = (wm * 64 + lr) * 128;    // + mf*2048
    int posB = (wn * 32 + lr) * 128;    // + nf*2048

    auto stage_unit = [&](int kt, int p) {   // stage tile kt's unit p into its buffer
        const char* src = (p == 0) ? aI + ((size_t)kt << 15)
                        : (p == 1) ? bI + ((size_t)kt << 15)
                        : (p == 2) ? bI + ((size_t)kt << 15) + 16384
                                   : aI + ((size_t)kt << 15) + 16384;
        char* dst = smem + (kt & 1) * 65536 + p * 16384 + stOff;
        load_lds16(src + stOff, dst);
        load_lds16(src + stOff + 8192, dst + 8192);
    };

#define RD_A(base)                                                                   \
    _Pragma("unroll")                                                                \
    for (int mf = 0; mf < 4; ++mf) {                                                 \
        af[mf][0] = *(const bf16x8*)((base) + posA + mf * 2048 + colx[0]);           \
        af[mf][1] = *(const bf16x8*)((base) + posA + mf * 2048 + colx[1]);           \
    }
#define RD_B(dstv, base)                                                             \
    _Pragma("unroll")                                                                \
    for (int nf = 0; nf < 2; ++nf) {                                                 \
        dstv[nf][0] = *(const bf16x8*)((base) + posB + nf * 2048 + colx[0]);         \
        dstv[nf][1] = *(const bf16x8*)((base) + posB + nf * 2048 + colx[1]);         \
    }
#define CLUSTER(MH, NH, BV)                                                          \
    __builtin_amdgcn_s_setprio(1);                                                   \
    _Pragma("unroll")                                                                \
    for (int mf = 0; mf < 4; ++mf)                                                   \
        _Pragma("unroll")                                                            \
        for (int nf = 0; nf < 2; ++nf)                                               \
            _Pragma("unroll")                                                        \
            for (int kk = 0; kk < 2; ++kk)                                           \
                acc[(MH)*4 + mf][(NH)*2 + nf] =                                      \
                    __builtin_amdgcn_mfma_f32_16x16x32_bf16(                         \
                        af[mf][kk], BV[nf][kk],                                      \
                        acc[(MH)*4 + mf][(NH)*2 + nf], 0, 0, 0);                     \
    __builtin_amdgcn_s_setprio(0);
#define BAR_SB() __builtin_amdgcn_s_barrier(); __builtin_amdgcn_sched_barrier(0);
#define VM6() asm volatile("s_waitcnt vmcnt(6)" ::: "memory");

    // prologue: tile 0's 4 units
    stage_unit(0, 0); stage_unit(0, 1); stage_unit(0, 2); stage_unit(0, 3);

    for (int t = 0; t < 31; ++t) {
        const char* tb = smem + (t & 1) * 65536;
        // phase 0: quadrant (mh0,nh0) — needs A0, B0
        stage_unit(t + 1, 0);
        VM6(); BAR_SB();
        RD_A(tb);
        RD_B(bf0, tb + 16384);
        CLUSTER(0, 0, bf0);
        // phase 1: (mh0,nh1) — needs B1 (af cached)
        stage_unit(t + 1, 1);
        VM6(); BAR_SB();
        RD_B(bf1, tb + 32768);
        CLUSTER(0, 1, bf1);
        // phase 2: (mh1,nh0) — needs A1 (bf0 cached)
        stage_unit(t + 1, 2);
        VM6(); BAR_SB();
        RD_A(tb + 49152);
        CLUSTER(1, 0, bf0);
        // phase 3: (mh1,nh1) — all cached
        stage_unit(t + 1, 3);
        VM6(); BAR_SB();
        CLUSTER(1, 1, bf1);
    }
    {   // peeled last tile t=31: no staging; drain with decreasing counted waits
        const char* tb = smem + 65536;   // 31&1 = 1
        asm volatile("s_waitcnt vmcnt(4)" ::: "memory"); BAR_SB();
        RD_A(tb);
        RD_B(bf0, tb + 16384);
        CLUSTER(0, 0, bf0);
        asm volatile("s_waitcnt vmcnt(2)" ::: "memory"); BAR_SB();
        RD_B(bf1, tb + 32768);
        CLUSTER(0, 1, bf1);
        asm volatile("s_waitcnt vmcnt(0)" ::: "memory"); BAR_SB();
        RD_A(tb + 49152);
        CLUSTER(1, 0, bf0);
        CLUSTER(1, 1, bf1);
    }

    // epilogue: C/D layout col=lane&15, row=(lane>>4)*4+q
    int orow0 = e * CAP + mt * 256 + wm * 128 + g * 4;
    int ocol0 = nt * 256 + wn * 64 + lr;
#pragma unroll
    for (int nf = 0; nf < 4; ++nf) {
        int oc = ocol0 + nf * 16;
        float bias = be[(size_t)e * DFF + oc];
#pragma unroll
        for (int mf = 0; mf < 8; ++mf) {
            int orow = orow0 + mf * 16;
#pragma unroll
            for (int q = 0; q < 4; ++q)
                out[(size_t)(orow + q) * DFF + oc] = acc[mf][nf][q] + bias;
        }
    }
#undef RD_A
#undef RD_B
#undef CLUSTER
#undef BAR_SB
#undef VM6
}

// ---------------- Kernel 4 (fallback): f32-B in-loop conversion (unit-layout A) -----
__global__ __launch_bounds__(512, 2) void moe_gemm_f32b(const char* __restrict__ abuf,
                                                        const float* __restrict__ we,
                                                        const float* __restrict__ be,
                                                        float* __restrict__ out) {
    __shared__ uint4 smem4[131072 / 16];
    char* smem = (char*)smem4;

    int bid = blockIdx.x;
    int e  = bid & 7;
    int r  = bid >> 3;
    int mt = r & 3;
    int nt = r >> 2;
    int tid = threadIdx.x, lane = tid & 63, wv = tid >> 6;
    int wm = wv >> 2, wn = wv & 3;
    int lr = lane & 15, g = lane >> 4;

    const char* aImg = abuf + (((size_t)((e * 4 + mt) * 32)) << 15);
    const float* bBase = we + (size_t)e * DM * DFF + (size_t)nt * 256 + lane * 4;
    int stOff = tid * 16;

    f32x4 acc[8][4] = {};
    float bs[16];

    auto issueB = [&](int kt, int h) {
        const float* bp = bBase + (size_t)(kt * 64 + wv * 8 + h * 4) * DFF;
#pragma unroll
        for (int j = 0; j < 4; ++j) {
            float4 t = *(const float4*)(bp + (size_t)j * DFF);
            bs[j * 4 + 0] = t.x; bs[j * 4 + 1] = t.y;
            bs[j * 4 + 2] = t.z; bs[j * 4 + 3] = t.w;
        }
    };
    auto issueA = [&](int kt, int buf) {
        const char* src = aImg + ((size_t)kt << 15) + stOff;
        char* dst = smem + buf * 65536 + stOff;
#pragma unroll
        for (int i = 0; i < 4; ++i) load_lds16(src + i * 8192, dst + i * 8192);
    };
    auto writeB = [&](int buf, int h) {
        char* bL = smem + buf * 65536 + 32768;
#pragma unroll
        for (int i = 0; i < 4; ++i) {
            int n = lane * 4 + i;
            ushort w[4];
#pragma unroll
            for (int j = 0; j < 4; ++j) {
                bf16_t b = (bf16_t)bs[j * 4 + i];
                w[j] = __builtin_bit_cast(unsigned short, b);
            }
            uint2 pk = { (unsigned)w[0] | ((unsigned)w[1] << 16),
                         (unsigned)w[2] | ((unsigned)w[3] << 16) };
            int slot = (n & 7) ^ ((n >> 3) & 7);
            *(uint2*)(bL + n * 128 + (((unsigned)(wv ^ slot)) << 4) + h * 8) = pk;
        }
    };

    issueA(0, 0);
    issueB(0, 0); writeB(0, 0);
    issueB(0, 1); writeB(0, 1);
    __syncthreads();

    int xa = lr & 7;
    int posA = (wm * 64 + lr) * 128;
    int bRow = wn * 64 + lr;

    for (int kt = 0; kt < 32; ++kt) {
        int cur = kt & 1, nxt = cur ^ 1;
        bool notlast = (kt < 31);
        const char* aC = smem + cur * 65536;
        const char* bC = aC + 32768;

        if (notlast) { issueA(kt + 1, nxt); issueB(kt + 1, 0); }
        __builtin_amdgcn_sched_barrier(0);

#pragma unroll
        for (int mh = 0; mh < 2; ++mh) {
            bf16x8 af[4][2];
#pragma unroll
            for (int mf = 0; mf < 4; ++mf) {
#pragma unroll
                for (int kk = 0; kk < 2; ++kk)
                    af[mf][kk] = *(const bf16x8*)(aC + mh * 16384 + posA + mf * 2048 +
                                                  (((kk * 4 + g) ^ xa) << 4));
            }
#pragma unroll
            for (int nh = 0; nh < 2; ++nh) {
                bf16x8 bfr[2][2];
#pragma unroll
                for (int nf = 0; nf < 2; ++nf) {
                    int rown = bRow + (nh * 2 + nf) * 16;
                    int xb = (rown & 7) ^ ((rown >> 3) & 7);
#pragma unroll
                    for (int kk = 0; kk < 2; ++kk)
                        bfr[nf][kk] = *(const bf16x8*)(bC + rown * 128 + (((kk * 4 + g) ^ xb) << 4));
                }
                __builtin_amdgcn_s_setprio(1);
#pragma unroll
                for (int mf = 0; mf < 4; ++mf)
#pragma unroll
                    for (int nf = 0; nf < 2; ++nf)
#pragma unroll
                        for (int kk = 0; kk < 2; ++kk)
                            acc[mh * 4 + mf][nh * 2 + nf] =
                                __builtin_amdgcn_mfma_f32_16x16x32_bf16(
                                    af[mf][kk], bfr[nf][kk],
                                    acc[mh * 4 + mf][nh * 2 + nf], 0, 0, 0);
                __builtin_amdgcn_s_setprio(0);
            }
            if (mh == 0 && notlast) { writeB(nxt, 0); issueB(kt + 1, 1); }
        }
        if (notlast) writeB(nxt, 1);
        __syncthreads();
    }

    int orow0 = e * CAP + mt * 256 + wm * 128 + g * 4;
    int ocol0 = nt * 256 + wn * 64 + lr;
#pragma unroll
    for (int nf = 0; nf < 4; ++nf) {
        int oc = ocol0 + nf * 16;
        float bias = be[(size_t)e * DFF + oc];
#pragma unroll
        for (int mf = 0; mf < 8; ++mf) {
            int orow = orow0 + mf * 16;
#pragma unroll
            for (int q = 0; q < 4; ++q)
                out[(size_t)(orow + q) * DFF + oc] = acc[mf][nf][q] + bias;
        }
    }
}

// ---------------- launcher ----------------------------------------------------------
extern "C" void kernel_launch(void* const* d_in, const int* in_sizes, int n_in,
                              void* d_out, int out_size, void* d_ws, size_t ws_size,
                              hipStream_t stream) {
    const float* x  = (const float*)d_in[0];
    const float* wg = (const float*)d_in[1];
    const float* we = (const float*)d_in[2];
    const float* be = (const float*)d_in[3];
    float* out = (float*)d_out;

    size_t needSmall = 65536 + (size_t)32 * 1048576;                 // meta + abuf
    size_t needBig   = needSmall + (size_t)256 * 1048576;            // + bbuf
    if (ws_size < needSmall) return;

    int* eidx  = (int*)d_ws;
    int* srcOf = eidx + S_TOK;
    char* abuf = (char*)d_ws + 65536;
    char* bbuf = abuf + (size_t)32 * 1048576;

    gate_argmax<<<S_TOK / 4, 256, 0, stream>>>(x, wg, eidx);
    scatter_slots<<<1, 64, 0, stream>>>(eidx, srcOf);
    pack_rows<<<S_TOK, 256, 0, stream>>>(x, srcOf, abuf);

    if (ws_size >= needBig) {
        convert_we<<<NE * 32 * 32, 256, 0, stream>>>(we, bbuf);
        moe_gemm_bf16<<<NE * 4 * 32, 512, 0, stream>>>(abuf, bbuf, be, out);
    } else {
        moe_gemm_f32b<<<NE * 4 * 32, 512, 0, stream>>>(abuf, we, be, out);
    }
}